// Round 6
// baseline (322.784 us; speedup 1.0000x reference)
//
#include <hip/hip_runtime.h>

#define TT 52          // tag count incl START/STOP
#define NT 50          // normal tags
#define START_TAG 50
#define STOP_TAG 51
#define BB 1024
#define SS 512
#define NWAVE 4        // waves per block (source-split)
#define NSRC 13        // sources per wave (4*13=52, guarded >= NT)
#define BPSTR 64       // fallback kernel LDS bp row stride

__device__ __forceinline__ int seq_len(const void* mask, int b, int j) {
    int cnt = 0;
    const unsigned* w = (const unsigned*)mask;
    unsigned w0 = w[0];
    unsigned w1 = w[1];
    if (w0 == 0x01010101u) {                       // bool / uint8
        const unsigned char* m = (const unsigned char*)mask + (size_t)b * SS;
        for (int k = j; k < SS; k += 64) cnt += (m[k] != 0);
    } else if (w0 == 0x3f800000u) {                // float32
        const float* m = (const float*)mask + (size_t)b * SS;
        for (int k = j; k < SS; k += 64) cnt += (m[k] != 0.f);
    } else if (w1 == 1u) {                         // int32
        const int* m = (const int*)mask + (size_t)b * SS;
        for (int k = j; k < SS; k += 64) cnt += (m[k] != 0);
    } else {                                       // int64
        const long long* m = (const long long*)mask + (size_t)b * SS;
        for (int k = j; k < SS; k += 64) cnt += (m[k] != 0);
    }
    for (int off = 32; off; off >>= 1) cnt += __shfl_xor(cnt, off, 64);
    return cnt > 0 ? cnt : 1;
}

// One DP step, 4-wave source-split version.
// Each wave: partial max over its 13 sources -> LDS exchange -> combine.
// Raw s_barrier (NOT __syncthreads) so the feats prefetch (vmcnt) stays
// outstanding across the barrier; lgkmcnt(0) gives LDS visibility.
#define DP_STEP(FREG, POSV)                                                       \
    {                                                                             \
        const int abits_ = __builtin_bit_cast(int, alpha);                        \
        float s_[NSRC];                                                           \
        _Pragma("unroll")                                                         \
        for (int i_ = 0; i_ < NSRC; ++i_)                                         \
            s_[i_] = __builtin_bit_cast(float,                                    \
                         __builtin_amdgcn_readlane(abits_, wbase + i_)) + tt[i_]; \
        float m0_ = fmaxf(fmaxf(s_[0], s_[1]), s_[2]);                            \
        float m1_ = fmaxf(fmaxf(s_[3], s_[4]), s_[5]);                            \
        float m2_ = fmaxf(fmaxf(s_[6], s_[7]), s_[8]);                            \
        float m3_ = fmaxf(fmaxf(s_[9], s_[10]), s_[11]);                          \
        float t0_ = fmaxf(fmaxf(m0_, m1_), m2_);                                  \
        float t1_ = fmaxf(m3_, s_[12]);                                           \
        float pm_ = fmaxf(t0_, t1_);                                              \
        ((float*)&pm_lds[(POSV) & 1][j])[w] = pm_;                                \
        asm volatile("s_waitcnt lgkmcnt(0)" ::: "memory");                        \
        __builtin_amdgcn_s_barrier();                                             \
        asm volatile("" ::: "memory");                                            \
        float4 q_ = pm_lds[(POSV) & 1][j];                                        \
        float bv_ = fmaxf(fmaxf(fmaxf(q_.x, q_.y), q_.z), q_.w);                  \
        if (w == 0) wsb[(size_t)(POSV) * 64] = bv_;                               \
        alpha = bv_ + (FREG);                                                     \
    }

// clamped feats load for lane's own tag (jc) at position p
#define FLD(P) fp[(size_t)((P) < SS ? (P) : SS - 1) * TT]

// ---------------- fast kernel: 4-wave split forward; value-match traceback --
__global__ __launch_bounds__(256, 4) void crf_viterbi_fast(
    const float* __restrict__ feats,   // [B,S,T]
    const void*  __restrict__ mask,    // [B,S]
    const float* __restrict__ trans,   // [T,T]
    float* __restrict__ ws,            // [B,S,64] bv history (128 MiB)
    int* __restrict__ out)             // [B,S]
{
    __shared__ float  trans_lds[64 * 53];   // [row i][col c], 53-padded
    __shared__ float4 pm_lds[2][64];        // [parity][j] partial maxes (w in .x..w)

    const int b   = blockIdx.x;
    const int tid = threadIdx.x;
    const int w   = tid >> 6;             // wave id 0..3
    const int j   = tid & 63;             // tag owned by this lane
    const int jc  = j < NT ? j : NT - 1;
    const int jr  = j * 53;
    const int wbase = w * NSRC;           // first source tag for this wave

    // stage trans rows into LDS (all 256 threads); rows >= NT get sentinel
    for (int k = tid; k < 64 * 53; k += 256) {
        int r = k / 53, c = k - r * 53;
        float v = -3.0e38f;
        if (r < NT && c < TT) v = trans[r * TT + c];
        trans_lds[k] = v;
    }

    const int len = seq_len(mask, b, j);  // identical in all 4 waves

    // this wave's 13 source-transition values trans[src][j]
    float tt[NSRC];
#pragma unroll
    for (int i = 0; i < NSRC; ++i) {
        int src = wbase + i;
        tt[i] = (src < NT) ? trans[src * TT + j] : -3.0e38f;
    }

    // init (pos 0): alpha0 = bv0 + f0 with bv0 = trans[START][j]
    const float* fp  = feats + ((size_t)b * SS) * TT + jc;
    float*       wsb = ws + ((size_t)b * SS) * 64 + j;
    const float bv0 = trans[START_TAG * TT + jc];
    float alpha = bv0 + fp[0];
    if (w == 0) wsb[0] = bv0;

    // ---- forward with 8-deep feats prefetch (two named 4-reg groups) ----
    // Invariant at loop top: fA = f[pos..pos+3], fB = f[pos+4..pos+7]
    float fA0 = FLD(1), fA1 = FLD(2), fA2 = FLD(3), fA3 = FLD(4);
    float fB0 = FLD(5), fB1 = FLD(6), fB2 = FLD(7), fB3 = FLD(8);

    int pos = 1;
    for (; pos + 7 < len; pos += 8) {
        DP_STEP(fA0, pos + 0)
        DP_STEP(fA1, pos + 1)
        DP_STEP(fA2, pos + 2)
        DP_STEP(fA3, pos + 3)
        fA0 = FLD(pos + 8);  fA1 = FLD(pos + 9);
        fA2 = FLD(pos + 10); fA3 = FLD(pos + 11);
        DP_STEP(fB0, pos + 4)
        DP_STEP(fB1, pos + 5)
        DP_STEP(fB2, pos + 6)
        DP_STEP(fB3, pos + 7)
        fB0 = FLD(pos + 12); fB1 = FLD(pos + 13);
        fB2 = FLD(pos + 14); fB3 = FLD(pos + 15);
    }
    // tail (<=7 steps); len identical across waves -> uniform branches, barrier-safe
    if (pos < len) { DP_STEP(fA0, pos) ++pos; }
    if (pos < len) { DP_STEP(fA1, pos) ++pos; }
    if (pos < len) { DP_STEP(fA2, pos) ++pos; }
    if (pos < len) { DP_STEP(fA3, pos) ++pos; }
    if (pos < len) { DP_STEP(fB0, pos) ++pos; }
    if (pos < len) { DP_STEP(fB1, pos) ++pos; }
    if (pos < len) { DP_STEP(fB2, pos) ++pos; }

    // ---- wave 0 finishes: best-last argmax, value-match traceback ----
    if (w != 0) return;

    float v = alpha + trans[jc * TT + STOP_TAG];
    if (j >= NT) v = -3.0e38f;
    int idx = j < NT ? j : 0;
    for (int off = 32; off; off >>= 1) {
        float vo = __shfl_xor(v, off, 64);
        int   io = __shfl_xor(idx, off, 64);
        if (vo > v || (vo == v && io < idx)) { v = vo; idx = io; }
    }

    int ptr = idx;
    int* ob = out + (size_t)b * SS;
    ob[len - 1] = ptr;

    const float* wsr   = ws + ((size_t)b * SS) * 64;      // + r*64 + j
    const float* fbase = feats + ((size_t)b * SS) * TT;   // + r*TT + jc

    float bvs[4], fs[4];
    float bv_cur;
    {
        int r0 = len - 1;
        bv_cur = wsr[(size_t)r0 * 64 + j];
#pragma unroll
        for (int k = 0; k < 4; ++k) {
            int r = len - 2 - k; int rc = r < 0 ? 0 : r;
            bvs[k] = wsr[(size_t)rc * 64 + j];
            fs[k]  = fbase[(size_t)rc * TT + jc];
        }
    }

    int tpos = len - 1;

#define TB_STEP(k)                                                              \
    {                                                                           \
        float bv_prev = bvs[k];                                                 \
        float alpha_prev = bv_prev + fs[k];                                     \
        float cand = alpha_prev + trans_lds[jr + ptr];                          \
        float candm = (j < NT) ? cand : -3.0e38f;                               \
        float tgt = __builtin_bit_cast(float,                                   \
            __builtin_amdgcn_readlane(__builtin_bit_cast(int, bv_cur), ptr));   \
        unsigned long long bm = __ballot(candm == tgt);                         \
        ptr = __ffsll(bm) - 1;                                                  \
        --tpos;                                                                 \
        ob[tpos] = ptr;                                                         \
        bv_cur = bv_prev;                                                       \
        int rc = tpos - 4; rc = rc < 0 ? 0 : rc;                                \
        bvs[k] = wsr[(size_t)rc * 64 + j];                                      \
        fs[k]  = fbase[(size_t)rc * TT + jc];                                   \
    }

    while (tpos >= 4) {
        TB_STEP(0) TB_STEP(1) TB_STEP(2) TB_STEP(3)
    }
#pragma unroll
    for (int k = 0; k < 3; ++k) {
        if (tpos >= 1) TB_STEP(k)
    }
#undef TB_STEP

    // zero-fill positions >= len
    for (int p = len + j; p < SS; p += 64) ob[p] = 0;
}

// ---------------- fallback (round-2 proven kernel, no workspace) ------------
__global__ __launch_bounds__(64, 1) void crf_viterbi(
    const float* __restrict__ feats,
    const void*  __restrict__ mask,
    const float* __restrict__ trans,
    int* __restrict__ out)
{
    __shared__ unsigned char bp_sh[SS * BPSTR];

    const int b = blockIdx.x;
    const int j = threadIdx.x;
    const int jc = j < NT ? j : NT - 1;

    const int len = seq_len(mask, b, j);

    float tt[NT];
#pragma unroll
    for (int i = 0; i < NT; ++i) tt[i] = trans[i * TT + j];

    const float* fp = feats + ((size_t)b * SS) * TT + jc;
    float alpha = trans[START_TAG * TT + jc] + fp[0];
    float fnext = fp[TT];

    for (int pos = 1; pos < len; ++pos) {
        const float f = fnext;
        { int np = pos + 1 < SS ? pos + 1 : SS - 1; fnext = fp[(size_t)np * TT]; }

        float best[4] = { -3.0e38f, -3.0e38f, -3.0e38f, -3.0e38f };
        int   bidx[4] = { 0, 0, 0, 0 };
        const int abits = __builtin_bit_cast(int, alpha);
#pragma unroll
        for (int i = 0; i < NT; ++i) {
            int ab = __builtin_amdgcn_readlane(abits, i);
            float s = __builtin_bit_cast(float, ab) + tt[i];
            const int c = i & 3;
            if (s > best[c]) { best[c] = s; bidx[c] = i; }
        }
        float bv = best[0]; int bi = bidx[0];
        if (best[1] > bv || (best[1] == bv && bidx[1] < bi)) { bv = best[1]; bi = bidx[1]; }
        if (best[2] > bv || (best[2] == bv && bidx[2] < bi)) { bv = best[2]; bi = bidx[2]; }
        if (best[3] > bv || (best[3] == bv && bidx[3] < bi)) { bv = best[3]; bi = bidx[3]; }

        alpha = bv + f;
        bp_sh[pos * BPSTR + j] = (unsigned char)bi;
    }

    float v = alpha + trans[jc * TT + STOP_TAG];
    if (j >= NT) v = -3.0e38f;
    int idx = j < NT ? j : 0;
    for (int off = 32; off; off >>= 1) {
        float vo = __shfl_xor(v, off, 64);
        int   io = __shfl_xor(idx, off, 64);
        if (vo > v || (vo == v && io < idx)) { v = vo; idx = io; }
    }

    __syncthreads();

    int ptr = idx;
    int* ob = out + (size_t)b * SS;
    for (int pos = len - 1; pos >= 1; --pos) {
        if (j == 0) ob[pos] = ptr;
        ptr = (int)bp_sh[pos * BPSTR + ptr];
    }
    if (j == 0) ob[0] = ptr;

    for (int p = len + j; p < SS; p += 64) ob[p] = 0;
}

extern "C" void kernel_launch(void* const* d_in, const int* in_sizes, int n_in,
                              void* d_out, int out_size, void* d_ws, size_t ws_size,
                              hipStream_t stream) {
    const float* feats = (const float*)d_in[0];
    const void*  mask  = d_in[1];
    // d_in[2] = tags, unused
    const float* trans = (const float*)d_in[3];
    int* out = (int*)d_out;

    const size_t need = (size_t)BB * SS * 64 * sizeof(float);   // 128 MiB
    if (ws_size >= need) {
        crf_viterbi_fast<<<dim3(BB), dim3(256), 0, stream>>>(feats, mask, trans,
                                                             (float*)d_ws, out);
    } else {
        crf_viterbi<<<dim3(BB), dim3(64), 0, stream>>>(feats, mask, trans, out);
    }
}

// Round 7
// 313.591 us; speedup vs baseline: 1.0293x; 1.0293x over previous
//
#include <hip/hip_runtime.h>

#define TT 52          // tag count incl START/STOP
#define NT 50          // normal tags
#define START_TAG 50
#define STOP_TAG 51
#define BB 1024
#define SS 512
#define BPSTR 64       // fallback kernel LDS bp row stride

__device__ __forceinline__ int seq_len(const void* mask, int b, int j) {
    int cnt = 0;
    const unsigned* w = (const unsigned*)mask;
    unsigned w0 = w[0];
    unsigned w1 = w[1];
    if (w0 == 0x01010101u) {                       // bool / uint8
        const unsigned char* m = (const unsigned char*)mask + (size_t)b * SS;
        for (int k = j; k < SS; k += 64) cnt += (m[k] != 0);
    } else if (w0 == 0x3f800000u) {                // float32
        const float* m = (const float*)mask + (size_t)b * SS;
        for (int k = j; k < SS; k += 64) cnt += (m[k] != 0.f);
    } else if (w1 == 1u) {                         // int32
        const int* m = (const int*)mask + (size_t)b * SS;
        for (int k = j; k < SS; k += 64) cnt += (m[k] != 0);
    } else {                                       // int64
        const long long* m = (const long long*)mask + (size_t)b * SS;
        for (int k = j; k < SS; k += 64) cnt += (m[k] != 0);
    }
    for (int off = 32; off; off >>= 1) cnt += __shfl_xor(cnt, off, 64);
    return cnt > 0 ? cnt : 1;
}

// One DP step: broadcast alpha[i] to all lanes via ds_bpermute (DS pipe, no
// SGPR hazards), add tt[i], exact max tree, store bv, alpha = bv + f.
// Bit-identical math to reference (same f32 adds, order-independent max).
#define DP_STEP(FREG, POSV)                                                       \
    {                                                                             \
        const int abits_ = __builtin_bit_cast(int, alpha);                        \
        float s_[NT];                                                             \
        _Pragma("unroll")                                                         \
        for (int i_ = 0; i_ < NT; ++i_) {                                         \
            int bi_ = __builtin_amdgcn_ds_bpermute(idx[i_], abits_);              \
            s_[i_] = __builtin_bit_cast(float, bi_) + tt[i_];                     \
        }                                                                         \
        float m_[17];                                                             \
        _Pragma("unroll")                                                         \
        for (int k_ = 0; k_ < 16; ++k_)                                           \
            m_[k_] = fmaxf(fmaxf(s_[3 * k_], s_[3 * k_ + 1]), s_[3 * k_ + 2]);    \
        m_[16] = fmaxf(s_[48], s_[49]);                                           \
        float n_[6];                                                              \
        _Pragma("unroll")                                                         \
        for (int k_ = 0; k_ < 5; ++k_)                                            \
            n_[k_] = fmaxf(fmaxf(m_[3 * k_], m_[3 * k_ + 1]), m_[3 * k_ + 2]);    \
        n_[5] = fmaxf(m_[15], m_[16]);                                            \
        float q0_ = fmaxf(fmaxf(n_[0], n_[1]), n_[2]);                            \
        float q1_ = fmaxf(fmaxf(n_[3], n_[4]), n_[5]);                            \
        float bv_ = fmaxf(q0_, q1_);                                              \
        wsb[(size_t)(POSV) * 64] = bv_;                                           \
        alpha = bv_ + (FREG);                                                     \
    }

// clamped feats load for lane's own tag (jc) at position p
#define FLD(P) fp[(size_t)((P) < SS ? (P) : SS - 1) * TT]

// ---------------- fast kernel: bpermute broadcast; value-match traceback ----
__global__ __launch_bounds__(64, 1) void crf_viterbi_fast(
    const float* __restrict__ feats,   // [B,S,T]
    const void*  __restrict__ mask,    // [B,S]
    const float* __restrict__ trans,   // [T,T]
    float* __restrict__ ws,            // [B,S,64] bv history (128 MiB)
    int* __restrict__ out)             // [B,S]
{
    __shared__ float trans_lds[64 * 53];   // [row i][col c], 53-padded

    const int b = blockIdx.x;
    const int j = threadIdx.x;
    const int jc = j < NT ? j : NT - 1;
    const int jr = j * 53;

    // stage trans rows into LDS; rows >= NT get -inf sentinel
    for (int k = j; k < 64 * 53; k += 64) {
        int r = k / 53, c = k - r * 53;
        float v = -3.0e38f;
        if (r < NT && c < TT) v = trans[r * TT + c];
        trans_lds[k] = v;
    }

    const int len = seq_len(mask, b, j);

    // transition column trans[0..49][j] into registers
    float tt[NT];
#pragma unroll
    for (int i = 0; i < NT; ++i) tt[i] = trans[i * TT + j];

    // broadcast indices i*4 pinned in VGPRs (opaque so they aren't re-mat'd)
    int idx[NT];
#pragma unroll
    for (int i = 0; i < NT; ++i) idx[i] = 4 * i;
#pragma unroll
    for (int i = 0; i < NT; ++i) asm("" : "+v"(idx[i]));

    // init (pos 0): alpha0 = bv0 + f0 with bv0 = trans[START][j]
    const float* fp = feats + ((size_t)b * SS) * TT + jc;
    float* wsb = ws + ((size_t)b * SS) * 64 + j;
    const float bv0 = trans[START_TAG * TT + jc];
    float alpha = bv0 + fp[0];
    wsb[0] = bv0;

    // ---- forward with 8-deep feats prefetch (two named 4-reg groups) ----
    // Invariant at loop top: fA = f[pos..pos+3], fB = f[pos+4..pos+7]
    float fA0 = FLD(1), fA1 = FLD(2), fA2 = FLD(3), fA3 = FLD(4);
    float fB0 = FLD(5), fB1 = FLD(6), fB2 = FLD(7), fB3 = FLD(8);

    int pos = 1;
    for (; pos + 7 < len; pos += 8) {
        DP_STEP(fA0, pos + 0)
        DP_STEP(fA1, pos + 1)
        DP_STEP(fA2, pos + 2)
        DP_STEP(fA3, pos + 3)
        fA0 = FLD(pos + 8);  fA1 = FLD(pos + 9);
        fA2 = FLD(pos + 10); fA3 = FLD(pos + 11);
        DP_STEP(fB0, pos + 4)
        DP_STEP(fB1, pos + 5)
        DP_STEP(fB2, pos + 6)
        DP_STEP(fB3, pos + 7)
        fB0 = FLD(pos + 12); fB1 = FLD(pos + 13);
        fB2 = FLD(pos + 14); fB3 = FLD(pos + 15);
    }
    // tail: fA = f[pos..pos+3], fB = f[pos+4..pos+7]; up to 7 steps remain
    if (pos < len) { DP_STEP(fA0, pos) ++pos; }
    if (pos < len) { DP_STEP(fA1, pos) ++pos; }
    if (pos < len) { DP_STEP(fA2, pos) ++pos; }
    if (pos < len) { DP_STEP(fA3, pos) ++pos; }
    if (pos < len) { DP_STEP(fB0, pos) ++pos; }
    if (pos < len) { DP_STEP(fB1, pos) ++pos; }
    if (pos < len) { DP_STEP(fB2, pos) ++pos; }

    // ---- best last tag ----
    float v = alpha + trans[jc * TT + STOP_TAG];
    if (j >= NT) v = -3.0e38f;
    int idxb = j < NT ? j : 0;
    for (int off = 32; off; off >>= 1) {
        float vo = __shfl_xor(v, off, 64);
        int   io = __shfl_xor(idxb, off, 64);
        if (vo > v || (vo == v && io < idxb)) { v = vo; idxb = io; }
    }

    __syncthreads();   // trans_lds staged (single wave; cheap)

    // ---- traceback by value matching ----
    int ptr = idxb;
    int* ob = out + (size_t)b * SS;
    ob[len - 1] = ptr;

    const float* wsr = ws + ((size_t)b * SS) * 64;        // + r*64 + j
    const float* fbase = feats + ((size_t)b * SS) * TT;   // + r*TT + jc

    float bvs[4], fs[4];
    float bv_cur;
    {
        int r0 = len - 1;
        bv_cur = wsr[(size_t)r0 * 64 + j];
#pragma unroll
        for (int k = 0; k < 4; ++k) {
            int r = len - 2 - k; int rc = r < 0 ? 0 : r;
            bvs[k] = wsr[(size_t)rc * 64 + j];
            fs[k]  = fbase[(size_t)rc * TT + jc];
        }
    }

    int tpos = len - 1;

#define TB_STEP(k)                                                              \
    {                                                                           \
        float bv_prev = bvs[k];                                                 \
        float alpha_prev = bv_prev + fs[k];                                     \
        float cand = alpha_prev + trans_lds[jr + ptr];                          \
        float candm = (j < NT) ? cand : -3.0e38f;                               \
        float tgt = __builtin_bit_cast(float,                                   \
            __builtin_amdgcn_readlane(__builtin_bit_cast(int, bv_cur), ptr));   \
        unsigned long long bm = __ballot(candm == tgt);                         \
        ptr = __ffsll(bm) - 1;                                                  \
        --tpos;                                                                 \
        ob[tpos] = ptr;                                                         \
        bv_cur = bv_prev;                                                       \
        int rc = tpos - 4; rc = rc < 0 ? 0 : rc;                                \
        bvs[k] = wsr[(size_t)rc * 64 + j];                                      \
        fs[k]  = fbase[(size_t)rc * TT + jc];                                   \
    }

    while (tpos >= 4) {
        TB_STEP(0) TB_STEP(1) TB_STEP(2) TB_STEP(3)
    }
#pragma unroll
    for (int k = 0; k < 3; ++k) {
        if (tpos >= 1) TB_STEP(k)
    }
#undef TB_STEP

    // zero-fill positions >= len
    for (int p = len + j; p < SS; p += 64) ob[p] = 0;
}

// ---------------- fallback (round-2 proven kernel, no workspace) ------------
__global__ __launch_bounds__(64, 1) void crf_viterbi(
    const float* __restrict__ feats,
    const void*  __restrict__ mask,
    const float* __restrict__ trans,
    int* __restrict__ out)
{
    __shared__ unsigned char bp_sh[SS * BPSTR];

    const int b = blockIdx.x;
    const int j = threadIdx.x;
    const int jc = j < NT ? j : NT - 1;

    const int len = seq_len(mask, b, j);

    float tt[NT];
#pragma unroll
    for (int i = 0; i < NT; ++i) tt[i] = trans[i * TT + j];

    const float* fp = feats + ((size_t)b * SS) * TT + jc;
    float alpha = trans[START_TAG * TT + jc] + fp[0];
    float fnext = fp[TT];

    for (int pos = 1; pos < len; ++pos) {
        const float f = fnext;
        { int np = pos + 1 < SS ? pos + 1 : SS - 1; fnext = fp[(size_t)np * TT]; }

        float best[4] = { -3.0e38f, -3.0e38f, -3.0e38f, -3.0e38f };
        int   bidx[4] = { 0, 0, 0, 0 };
        const int abits = __builtin_bit_cast(int, alpha);
#pragma unroll
        for (int i = 0; i < NT; ++i) {
            int ab = __builtin_amdgcn_readlane(abits, i);
            float s = __builtin_bit_cast(float, ab) + tt[i];
            const int c = i & 3;
            if (s > best[c]) { best[c] = s; bidx[c] = i; }
        }
        float bv = best[0]; int bi = bidx[0];
        if (best[1] > bv || (best[1] == bv && bidx[1] < bi)) { bv = best[1]; bi = bidx[1]; }
        if (best[2] > bv || (best[2] == bv && bidx[2] < bi)) { bv = best[2]; bi = bidx[2]; }
        if (best[3] > bv || (best[3] == bv && bidx[3] < bi)) { bv = best[3]; bi = bidx[3]; }

        alpha = bv + f;
        bp_sh[pos * BPSTR + j] = (unsigned char)bi;
    }

    float v = alpha + trans[jc * TT + STOP_TAG];
    if (j >= NT) v = -3.0e38f;
    int idx = j < NT ? j : 0;
    for (int off = 32; off; off >>= 1) {
        float vo = __shfl_xor(v, off, 64);
        int   io = __shfl_xor(idx, off, 64);
        if (vo > v || (vo == v && io < idx)) { v = vo; idx = io; }
    }

    __syncthreads();

    int ptr = idx;
    int* ob = out + (size_t)b * SS;
    for (int pos = len - 1; pos >= 1; --pos) {
        if (j == 0) ob[pos] = ptr;
        ptr = (int)bp_sh[pos * BPSTR + ptr];
    }
    if (j == 0) ob[0] = ptr;

    for (int p = len + j; p < SS; p += 64) ob[p] = 0;
}

extern "C" void kernel_launch(void* const* d_in, const int* in_sizes, int n_in,
                              void* d_out, int out_size, void* d_ws, size_t ws_size,
                              hipStream_t stream) {
    const float* feats = (const float*)d_in[0];
    const void*  mask  = d_in[1];
    // d_in[2] = tags, unused
    const float* trans = (const float*)d_in[3];
    int* out = (int*)d_out;

    const size_t need = (size_t)BB * SS * 64 * sizeof(float);   // 128 MiB
    if (ws_size >= need) {
        crf_viterbi_fast<<<dim3(BB), dim3(64), 0, stream>>>(feats, mask, trans,
                                                            (float*)d_ws, out);
    } else {
        crf_viterbi<<<dim3(BB), dim3(64), 0, stream>>>(feats, mask, trans, out);
    }
}

// Round 8
// 195.502 us; speedup vs baseline: 1.6511x; 1.6040x over previous
//
#include <hip/hip_runtime.h>

#define TT 52          // tag count incl START/STOP
#define NT 50          // normal tags
#define START_TAG 50
#define STOP_TAG 51
#define BB 1024
#define SS 512
#define BPSTR 64       // fallback kernel LDS bp row stride

__device__ __forceinline__ int seq_len(const void* mask, int b, int j) {
    int cnt = 0;
    const unsigned* w = (const unsigned*)mask;
    unsigned w0 = w[0];
    unsigned w1 = w[1];
    if (w0 == 0x01010101u) {                       // bool / uint8
        const unsigned char* m = (const unsigned char*)mask + (size_t)b * SS;
        for (int k = j; k < SS; k += 64) cnt += (m[k] != 0);
    } else if (w0 == 0x3f800000u) {                // float32
        const float* m = (const float*)mask + (size_t)b * SS;
        for (int k = j; k < SS; k += 64) cnt += (m[k] != 0.f);
    } else if (w1 == 1u) {                         // int32
        const int* m = (const int*)mask + (size_t)b * SS;
        for (int k = j; k < SS; k += 64) cnt += (m[k] != 0);
    } else {                                       // int64
        const long long* m = (const long long*)mask + (size_t)b * SS;
        for (int k = j; k < SS; k += 64) cnt += (m[k] != 0);
    }
    for (int off = 32; off; off >>= 1) cnt += __shfl_xor(cnt, off, 64);
    return cnt > 0 ? cnt : 1;
}

#define RL(i_) __builtin_bit_cast(float, __builtin_amdgcn_readlane(abits_, (i_)))

// One DP step, hazard-pipelined: readlanes chunked 17/17/16 with
// sched_barrier(0) fences so each v_add reads an SGPR written >=17
// instructions earlier (avoids the VALU-writes-SGPR -> VALU-reads-SGPR
// wait states). Math bit-identical to reference (same f32 adds, exact
// order-independent max tree).
#define DP_STEP(FREG, POSV)                                                       \
    {                                                                             \
        const int abits_ = __builtin_bit_cast(int, alpha);                        \
        float a_[NT];                                                             \
        float s_[NT];                                                             \
        _Pragma("unroll")                                                         \
        for (int i_ = 0; i_ < 17; ++i_) a_[i_] = RL(i_);                          \
        __builtin_amdgcn_sched_barrier(0);                                        \
        _Pragma("unroll")                                                         \
        for (int i_ = 17; i_ < 34; ++i_) a_[i_] = RL(i_);                         \
        _Pragma("unroll")                                                         \
        for (int i_ = 0; i_ < 17; ++i_) s_[i_] = a_[i_] + tt[i_];                 \
        __builtin_amdgcn_sched_barrier(0);                                        \
        _Pragma("unroll")                                                         \
        for (int i_ = 34; i_ < NT; ++i_) a_[i_] = RL(i_);                         \
        _Pragma("unroll")                                                         \
        for (int i_ = 17; i_ < 34; ++i_) s_[i_] = a_[i_] + tt[i_];                \
        __builtin_amdgcn_sched_barrier(0);                                        \
        _Pragma("unroll")                                                         \
        for (int i_ = 34; i_ < NT; ++i_) s_[i_] = a_[i_] + tt[i_];                \
        float m_[17];                                                             \
        _Pragma("unroll")                                                         \
        for (int k_ = 0; k_ < 16; ++k_)                                           \
            m_[k_] = fmaxf(fmaxf(s_[3 * k_], s_[3 * k_ + 1]), s_[3 * k_ + 2]);    \
        m_[16] = fmaxf(s_[48], s_[49]);                                           \
        float n_[6];                                                              \
        _Pragma("unroll")                                                         \
        for (int k_ = 0; k_ < 5; ++k_)                                            \
            n_[k_] = fmaxf(fmaxf(m_[3 * k_], m_[3 * k_ + 1]), m_[3 * k_ + 2]);    \
        n_[5] = fmaxf(m_[15], m_[16]);                                            \
        float q0_ = fmaxf(fmaxf(n_[0], n_[1]), n_[2]);                            \
        float q1_ = fmaxf(fmaxf(n_[3], n_[4]), n_[5]);                            \
        float bv_ = fmaxf(q0_, q1_);                                              \
        wsb[(size_t)(POSV) * 64] = bv_;                                           \
        alpha = bv_ + (FREG);                                                     \
    }

// clamped feats load for lane's own tag (jc) at position p
#define FLD(P) fp[(size_t)((P) < SS ? (P) : SS - 1) * TT]

// ---------------- fast kernel: pipelined readlane fwd; value-match tb -------
__global__ __launch_bounds__(64, 1) void crf_viterbi_fast(
    const float* __restrict__ feats,   // [B,S,T]
    const void*  __restrict__ mask,    // [B,S]
    const float* __restrict__ trans,   // [T,T]
    float* __restrict__ ws,            // [B,S,64] bv history (128 MiB)
    int* __restrict__ out)             // [B,S]
{
    __shared__ float trans_lds[64 * 53];   // [row i][col c], 53-padded

    const int b = blockIdx.x;
    const int j = threadIdx.x;
    const int jc = j < NT ? j : NT - 1;
    const int jr = j * 53;

    // stage trans rows into LDS; rows >= NT get -inf sentinel
    for (int k = j; k < 64 * 53; k += 64) {
        int r = k / 53, c = k - r * 53;
        float v = -3.0e38f;
        if (r < NT && c < TT) v = trans[r * TT + c];
        trans_lds[k] = v;
    }

    const int len = seq_len(mask, b, j);

    // transition column trans[0..49][j] into registers
    float tt[NT];
#pragma unroll
    for (int i = 0; i < NT; ++i) tt[i] = trans[i * TT + j];

    // init (pos 0): alpha0 = bv0 + f0 with bv0 = trans[START][j]
    const float* fp = feats + ((size_t)b * SS) * TT + jc;
    float* wsb = ws + ((size_t)b * SS) * 64 + j;
    const float bv0 = trans[START_TAG * TT + jc];
    float alpha = bv0 + fp[0];
    wsb[0] = bv0;

    // ---- forward with 8-deep feats prefetch (two named 4-reg groups) ----
    // Invariant at loop top: fA = f[pos..pos+3], fB = f[pos+4..pos+7]
    float fA0 = FLD(1), fA1 = FLD(2), fA2 = FLD(3), fA3 = FLD(4);
    float fB0 = FLD(5), fB1 = FLD(6), fB2 = FLD(7), fB3 = FLD(8);

    int pos = 1;
    for (; pos + 7 < len; pos += 8) {
        DP_STEP(fA0, pos + 0)
        DP_STEP(fA1, pos + 1)
        DP_STEP(fA2, pos + 2)
        DP_STEP(fA3, pos + 3)
        fA0 = FLD(pos + 8);  fA1 = FLD(pos + 9);
        fA2 = FLD(pos + 10); fA3 = FLD(pos + 11);
        DP_STEP(fB0, pos + 4)
        DP_STEP(fB1, pos + 5)
        DP_STEP(fB2, pos + 6)
        DP_STEP(fB3, pos + 7)
        fB0 = FLD(pos + 12); fB1 = FLD(pos + 13);
        fB2 = FLD(pos + 14); fB3 = FLD(pos + 15);
    }
    // tail: fA = f[pos..pos+3], fB = f[pos+4..pos+7]; up to 7 steps remain
    if (pos < len) { DP_STEP(fA0, pos) ++pos; }
    if (pos < len) { DP_STEP(fA1, pos) ++pos; }
    if (pos < len) { DP_STEP(fA2, pos) ++pos; }
    if (pos < len) { DP_STEP(fA3, pos) ++pos; }
    if (pos < len) { DP_STEP(fB0, pos) ++pos; }
    if (pos < len) { DP_STEP(fB1, pos) ++pos; }
    if (pos < len) { DP_STEP(fB2, pos) ++pos; }

    // ---- best last tag ----
    float v = alpha + trans[jc * TT + STOP_TAG];
    if (j >= NT) v = -3.0e38f;
    int idxb = j < NT ? j : 0;
    for (int off = 32; off; off >>= 1) {
        float vo = __shfl_xor(v, off, 64);
        int   io = __shfl_xor(idxb, off, 64);
        if (vo > v || (vo == v && io < idxb)) { v = vo; idxb = io; }
    }

    __syncthreads();   // trans_lds staged (single wave; cheap)

    // ---- traceback by value matching ----
    int ptr = idxb;
    int* ob = out + (size_t)b * SS;
    ob[len - 1] = ptr;

    const float* wsr = ws + ((size_t)b * SS) * 64;        // + r*64 + j
    const float* fbase = feats + ((size_t)b * SS) * TT;   // + r*TT + jc

    float bvs[4], fs[4];
    float bv_cur;
    {
        int r0 = len - 1;
        bv_cur = wsr[(size_t)r0 * 64 + j];
#pragma unroll
        for (int k = 0; k < 4; ++k) {
            int r = len - 2 - k; int rc = r < 0 ? 0 : r;
            bvs[k] = wsr[(size_t)rc * 64 + j];
            fs[k]  = fbase[(size_t)rc * TT + jc];
        }
    }

    int tpos = len - 1;

#define TB_STEP(k)                                                              \
    {                                                                           \
        float bv_prev = bvs[k];                                                 \
        float alpha_prev = bv_prev + fs[k];                                     \
        float cand = alpha_prev + trans_lds[jr + ptr];                          \
        float candm = (j < NT) ? cand : -3.0e38f;                               \
        float tgt = __builtin_bit_cast(float,                                   \
            __builtin_amdgcn_readlane(__builtin_bit_cast(int, bv_cur), ptr));   \
        unsigned long long bm = __ballot(candm == tgt);                         \
        ptr = __ffsll(bm) - 1;                                                  \
        --tpos;                                                                 \
        ob[tpos] = ptr;                                                         \
        bv_cur = bv_prev;                                                       \
        int rc = tpos - 4; rc = rc < 0 ? 0 : rc;                                \
        bvs[k] = wsr[(size_t)rc * 64 + j];                                      \
        fs[k]  = fbase[(size_t)rc * TT + jc];                                   \
    }

    while (tpos >= 4) {
        TB_STEP(0) TB_STEP(1) TB_STEP(2) TB_STEP(3)
    }
#pragma unroll
    for (int k = 0; k < 3; ++k) {
        if (tpos >= 1) TB_STEP(k)
    }
#undef TB_STEP

    // zero-fill positions >= len
    for (int p = len + j; p < SS; p += 64) ob[p] = 0;
}

// ---------------- fallback (round-2 proven kernel, no workspace) ------------
__global__ __launch_bounds__(64, 1) void crf_viterbi(
    const float* __restrict__ feats,
    const void*  __restrict__ mask,
    const float* __restrict__ trans,
    int* __restrict__ out)
{
    __shared__ unsigned char bp_sh[SS * BPSTR];

    const int b = blockIdx.x;
    const int j = threadIdx.x;
    const int jc = j < NT ? j : NT - 1;

    const int len = seq_len(mask, b, j);

    float tt[NT];
#pragma unroll
    for (int i = 0; i < NT; ++i) tt[i] = trans[i * TT + j];

    const float* fp = feats + ((size_t)b * SS) * TT + jc;
    float alpha = trans[START_TAG * TT + jc] + fp[0];
    float fnext = fp[TT];

    for (int pos = 1; pos < len; ++pos) {
        const float f = fnext;
        { int np = pos + 1 < SS ? pos + 1 : SS - 1; fnext = fp[(size_t)np * TT]; }

        float best[4] = { -3.0e38f, -3.0e38f, -3.0e38f, -3.0e38f };
        int   bidx[4] = { 0, 0, 0, 0 };
        const int abits = __builtin_bit_cast(int, alpha);
#pragma unroll
        for (int i = 0; i < NT; ++i) {
            int ab = __builtin_amdgcn_readlane(abits, i);
            float s = __builtin_bit_cast(float, ab) + tt[i];
            const int c = i & 3;
            if (s > best[c]) { best[c] = s; bidx[c] = i; }
        }
        float bv = best[0]; int bi = bidx[0];
        if (best[1] > bv || (best[1] == bv && bidx[1] < bi)) { bv = best[1]; bi = bidx[1]; }
        if (best[2] > bv || (best[2] == bv && bidx[2] < bi)) { bv = best[2]; bi = bidx[2]; }
        if (best[3] > bv || (best[3] == bv && bidx[3] < bi)) { bv = best[3]; bi = bidx[3]; }

        alpha = bv + f;
        bp_sh[pos * BPSTR + j] = (unsigned char)bi;
    }

    float v = alpha + trans[jc * TT + STOP_TAG];
    if (j >= NT) v = -3.0e38f;
    int idx = j < NT ? j : 0;
    for (int off = 32; off; off >>= 1) {
        float vo = __shfl_xor(v, off, 64);
        int   io = __shfl_xor(idx, off, 64);
        if (vo > v || (vo == v && io < idx)) { v = vo; idx = io; }
    }

    __syncthreads();

    int ptr = idx;
    int* ob = out + (size_t)b * SS;
    for (int pos = len - 1; pos >= 1; --pos) {
        if (j == 0) ob[pos] = ptr;
        ptr = (int)bp_sh[pos * BPSTR + ptr];
    }
    if (j == 0) ob[0] = ptr;

    for (int p = len + j; p < SS; p += 64) ob[p] = 0;
}

extern "C" void kernel_launch(void* const* d_in, const int* in_sizes, int n_in,
                              void* d_out, int out_size, void* d_ws, size_t ws_size,
                              hipStream_t stream) {
    const float* feats = (const float*)d_in[0];
    const void*  mask  = d_in[1];
    // d_in[2] = tags, unused
    const float* trans = (const float*)d_in[3];
    int* out = (int*)d_out;

    const size_t need = (size_t)BB * SS * 64 * sizeof(float);   // 128 MiB
    if (ws_size >= need) {
        crf_viterbi_fast<<<dim3(BB), dim3(64), 0, stream>>>(feats, mask, trans,
                                                            (float*)d_ws, out);
    } else {
        crf_viterbi<<<dim3(BB), dim3(64), 0, stream>>>(feats, mask, trans, out);
    }
}

// Round 9
// 170.697 us; speedup vs baseline: 1.8910x; 1.1453x over previous
//
#include <hip/hip_runtime.h>

#define TT 52          // tag count incl START/STOP
#define NT 50          // normal tags
#define START_TAG 50
#define STOP_TAG 51
#define BB 1024
#define SS 512
#define BPSTR 64       // fallback kernel LDS bp row stride

__device__ __forceinline__ int seq_len(const void* mask, int b, int j) {
    int cnt = 0;
    const unsigned* w = (const unsigned*)mask;
    unsigned w0 = w[0];
    unsigned w1 = w[1];
    if (w0 == 0x01010101u) {                       // bool / uint8
        const unsigned char* m = (const unsigned char*)mask + (size_t)b * SS;
        for (int k = j; k < SS; k += 64) cnt += (m[k] != 0);
    } else if (w0 == 0x3f800000u) {                // float32
        const float* m = (const float*)mask + (size_t)b * SS;
        for (int k = j; k < SS; k += 64) cnt += (m[k] != 0.f);
    } else if (w1 == 1u) {                         // int32
        const int* m = (const int*)mask + (size_t)b * SS;
        for (int k = j; k < SS; k += 64) cnt += (m[k] != 0);
    } else {                                       // int64
        const long long* m = (const long long*)mask + (size_t)b * SS;
        for (int k = j; k < SS; k += 64) cnt += (m[k] != 0);
    }
    for (int off = 32; off; off >>= 1) cnt += __shfl_xor(cnt, off, 64);
    return cnt > 0 ? cnt : 1;
}

// One DP step: broadcast alpha via LDS (1 ds_write_b32 + 13 ds_read_b128,
// broadcast -> conflict-free), add tt, exact max3 tree, store bv, alpha=bv+f.
// No barrier needed (single wave; per-wave LDS ops are ordered; compiler
// emits fine-grained lgkmcnt). Double-buffered by step parity (compile-time
// constant in the unroll-8 body). Bit-identical math to reference.
#define DP_STEP(FREG, POSV)                                                       \
    {                                                                             \
        a_sh[(POSV) & 1][j] = alpha;                                              \
        float q_[52];                                                             \
        _Pragma("unroll")                                                         \
        for (int r_ = 0; r_ < 13; ++r_) {                                         \
            float4 t4_ = ((const float4*)a_sh[(POSV) & 1])[r_];                   \
            q_[4 * r_ + 0] = t4_.x; q_[4 * r_ + 1] = t4_.y;                       \
            q_[4 * r_ + 2] = t4_.z; q_[4 * r_ + 3] = t4_.w;                       \
        }                                                                         \
        float s_[NT];                                                             \
        _Pragma("unroll")                                                         \
        for (int i_ = 0; i_ < NT; ++i_) s_[i_] = q_[i_] + tt[i_];                 \
        float m_[17];                                                             \
        _Pragma("unroll")                                                         \
        for (int k_ = 0; k_ < 16; ++k_)                                           \
            m_[k_] = fmaxf(fmaxf(s_[3 * k_], s_[3 * k_ + 1]), s_[3 * k_ + 2]);    \
        m_[16] = fmaxf(s_[48], s_[49]);                                           \
        float n_[6];                                                              \
        _Pragma("unroll")                                                         \
        for (int k_ = 0; k_ < 5; ++k_)                                            \
            n_[k_] = fmaxf(fmaxf(m_[3 * k_], m_[3 * k_ + 1]), m_[3 * k_ + 2]);    \
        n_[5] = fmaxf(m_[15], m_[16]);                                            \
        float q0_ = fmaxf(fmaxf(n_[0], n_[1]), n_[2]);                            \
        float q1_ = fmaxf(fmaxf(n_[3], n_[4]), n_[5]);                            \
        float bv_ = fmaxf(q0_, q1_);                                              \
        wsb[(size_t)(POSV) * 64] = bv_;                                           \
        alpha = bv_ + (FREG);                                                     \
    }

// clamped feats load for lane's own tag (jc) at position p
#define FLD(P) fp[(size_t)((P) < SS ? (P) : SS - 1) * TT]

// ---------------- fast kernel: LDS-broadcast fwd; value-match traceback -----
__global__ __launch_bounds__(64, 1) void crf_viterbi_fast(
    const float* __restrict__ feats,   // [B,S,T]
    const void*  __restrict__ mask,    // [B,S]
    const float* __restrict__ trans,   // [T,T]
    float* __restrict__ ws,            // [B,S,64] bv history (128 MiB)
    int* __restrict__ out)             // [B,S]
{
    __shared__ float trans_lds[64 * 53];                    // [row i][col c], 53-padded
    __shared__ __align__(16) float a_sh[2][64];             // alpha broadcast, dbuf by parity

    const int b = blockIdx.x;
    const int j = threadIdx.x;
    const int jc = j < NT ? j : NT - 1;
    const int jr = j * 53;

    // stage trans rows into LDS; rows >= NT get -inf sentinel
    for (int k = j; k < 64 * 53; k += 64) {
        int r = k / 53, c = k - r * 53;
        float v = -3.0e38f;
        if (r < NT && c < TT) v = trans[r * TT + c];
        trans_lds[k] = v;
    }

    const int len = seq_len(mask, b, j);

    // transition column trans[0..49][j] into registers
    float tt[NT];
#pragma unroll
    for (int i = 0; i < NT; ++i) tt[i] = trans[i * TT + j];  // j<=63: in bounds (2611<2704)

    // init (pos 0): alpha0 = bv0 + f0 with bv0 = trans[START][j]
    const float* fp = feats + ((size_t)b * SS) * TT + jc;
    float* wsb = ws + ((size_t)b * SS) * 64 + j;
    const float bv0 = trans[START_TAG * TT + jc];
    float alpha = bv0 + fp[0];
    wsb[0] = bv0;

    // ---- forward with 8-deep feats prefetch (two named 4-reg groups) ----
    // Invariant at loop top: fA = f[pos..pos+3], fB = f[pos+4..pos+7]
    float fA0 = FLD(1), fA1 = FLD(2), fA2 = FLD(3), fA3 = FLD(4);
    float fB0 = FLD(5), fB1 = FLD(6), fB2 = FLD(7), fB3 = FLD(8);

    int pos = 1;
    for (; pos + 7 < len; pos += 8) {
        DP_STEP(fA0, pos + 0)
        DP_STEP(fA1, pos + 1)
        DP_STEP(fA2, pos + 2)
        DP_STEP(fA3, pos + 3)
        fA0 = FLD(pos + 8);  fA1 = FLD(pos + 9);
        fA2 = FLD(pos + 10); fA3 = FLD(pos + 11);
        DP_STEP(fB0, pos + 4)
        DP_STEP(fB1, pos + 5)
        DP_STEP(fB2, pos + 6)
        DP_STEP(fB3, pos + 7)
        fB0 = FLD(pos + 12); fB1 = FLD(pos + 13);
        fB2 = FLD(pos + 14); fB3 = FLD(pos + 15);
    }
    // tail: fA = f[pos..pos+3], fB = f[pos+4..pos+7]; up to 7 steps remain
    if (pos < len) { DP_STEP(fA0, pos) ++pos; }
    if (pos < len) { DP_STEP(fA1, pos) ++pos; }
    if (pos < len) { DP_STEP(fA2, pos) ++pos; }
    if (pos < len) { DP_STEP(fA3, pos) ++pos; }
    if (pos < len) { DP_STEP(fB0, pos) ++pos; }
    if (pos < len) { DP_STEP(fB1, pos) ++pos; }
    if (pos < len) { DP_STEP(fB2, pos) ++pos; }

    // ---- best last tag ----
    float v = alpha + trans[jc * TT + STOP_TAG];
    if (j >= NT) v = -3.0e38f;
    int idxb = j < NT ? j : 0;
    for (int off = 32; off; off >>= 1) {
        float vo = __shfl_xor(v, off, 64);
        int   io = __shfl_xor(idxb, off, 64);
        if (vo > v || (vo == v && io < idxb)) { v = vo; idxb = io; }
    }

    __syncthreads();   // one-time; trans_lds visibility before traceback

    // ---- traceback by value matching ----
    int ptr = idxb;
    int* ob = out + (size_t)b * SS;
    ob[len - 1] = ptr;

    const float* wsr = ws + ((size_t)b * SS) * 64;        // + r*64 + j
    const float* fbase = feats + ((size_t)b * SS) * TT;   // + r*TT + jc

    float bvs[4], fs[4];
    float bv_cur;
    {
        int r0 = len - 1;
        bv_cur = wsr[(size_t)r0 * 64 + j];
#pragma unroll
        for (int k = 0; k < 4; ++k) {
            int r = len - 2 - k; int rc = r < 0 ? 0 : r;
            bvs[k] = wsr[(size_t)rc * 64 + j];
            fs[k]  = fbase[(size_t)rc * TT + jc];
        }
    }

    int tpos = len - 1;

#define TB_STEP(k)                                                              \
    {                                                                           \
        float bv_prev = bvs[k];                                                 \
        float alpha_prev = bv_prev + fs[k];                                     \
        float cand = alpha_prev + trans_lds[jr + ptr];                          \
        float candm = (j < NT) ? cand : -3.0e38f;                               \
        float tgt = __builtin_bit_cast(float,                                   \
            __builtin_amdgcn_readlane(__builtin_bit_cast(int, bv_cur), ptr));   \
        unsigned long long bm = __ballot(candm == tgt);                         \
        ptr = __ffsll(bm) - 1;                                                  \
        --tpos;                                                                 \
        ob[tpos] = ptr;                                                         \
        bv_cur = bv_prev;                                                       \
        int rc = tpos - 4; rc = rc < 0 ? 0 : rc;                                \
        bvs[k] = wsr[(size_t)rc * 64 + j];                                      \
        fs[k]  = fbase[(size_t)rc * TT + jc];                                   \
    }

    while (tpos >= 4) {
        TB_STEP(0) TB_STEP(1) TB_STEP(2) TB_STEP(3)
    }
#pragma unroll
    for (int k = 0; k < 3; ++k) {
        if (tpos >= 1) TB_STEP(k)
    }
#undef TB_STEP

    // zero-fill positions >= len
    for (int p = len + j; p < SS; p += 64) ob[p] = 0;
}

// ---------------- fallback (round-2 proven kernel, no workspace) ------------
__global__ __launch_bounds__(64, 1) void crf_viterbi(
    const float* __restrict__ feats,
    const void*  __restrict__ mask,
    const float* __restrict__ trans,
    int* __restrict__ out)
{
    __shared__ unsigned char bp_sh[SS * BPSTR];

    const int b = blockIdx.x;
    const int j = threadIdx.x;
    const int jc = j < NT ? j : NT - 1;

    const int len = seq_len(mask, b, j);

    float tt[NT];
#pragma unroll
    for (int i = 0; i < NT; ++i) tt[i] = trans[i * TT + j];

    const float* fp = feats + ((size_t)b * SS) * TT + jc;
    float alpha = trans[START_TAG * TT + jc] + fp[0];
    float fnext = fp[TT];

    for (int pos = 1; pos < len; ++pos) {
        const float f = fnext;
        { int np = pos + 1 < SS ? pos + 1 : SS - 1; fnext = fp[(size_t)np * TT]; }

        float best[4] = { -3.0e38f, -3.0e38f, -3.0e38f, -3.0e38f };
        int   bidx[4] = { 0, 0, 0, 0 };
        const int abits = __builtin_bit_cast(int, alpha);
#pragma unroll
        for (int i = 0; i < NT; ++i) {
            int ab = __builtin_amdgcn_readlane(abits, i);
            float s = __builtin_bit_cast(float, ab) + tt[i];
            const int c = i & 3;
            if (s > best[c]) { best[c] = s; bidx[c] = i; }
        }
        float bv = best[0]; int bi = bidx[0];
        if (best[1] > bv || (best[1] == bv && bidx[1] < bi)) { bv = best[1]; bi = bidx[1]; }
        if (best[2] > bv || (best[2] == bv && bidx[2] < bi)) { bv = best[2]; bi = bidx[2]; }
        if (best[3] > bv || (best[3] == bv && bidx[3] < bi)) { bv = best[3]; bi = bidx[3]; }

        alpha = bv + f;
        bp_sh[pos * BPSTR + j] = (unsigned char)bi;
    }

    float v = alpha + trans[jc * TT + STOP_TAG];
    if (j >= NT) v = -3.0e38f;
    int idx = j < NT ? j : 0;
    for (int off = 32; off; off >>= 1) {
        float vo = __shfl_xor(v, off, 64);
        int   io = __shfl_xor(idx, off, 64);
        if (vo > v || (vo == v && io < idx)) { v = vo; idx = io; }
    }

    __syncthreads();

    int ptr = idx;
    int* ob = out + (size_t)b * SS;
    for (int pos = len - 1; pos >= 1; --pos) {
        if (j == 0) ob[pos] = ptr;
        ptr = (int)bp_sh[pos * BPSTR + ptr];
    }
    if (j == 0) ob[0] = ptr;

    for (int p = len + j; p < SS; p += 64) ob[p] = 0;
}

extern "C" void kernel_launch(void* const* d_in, const int* in_sizes, int n_in,
                              void* d_out, int out_size, void* d_ws, size_t ws_size,
                              hipStream_t stream) {
    const float* feats = (const float*)d_in[0];
    const void*  mask  = d_in[1];
    // d_in[2] = tags, unused
    const float* trans = (const float*)d_in[3];
    int* out = (int*)d_out;

    const size_t need = (size_t)BB * SS * 64 * sizeof(float);   // 128 MiB
    if (ws_size >= need) {
        crf_viterbi_fast<<<dim3(BB), dim3(64), 0, stream>>>(feats, mask, trans,
                                                            (float*)d_ws, out);
    } else {
        crf_viterbi<<<dim3(BB), dim3(64), 0, stream>>>(feats, mask, trans, out);
    }
}